// Round 2
// baseline (6631.750 us; speedup 1.0000x reference)
//
#include <hip/hip_runtime.h>
#include <math.h>
#include <stdint.h>

// Greedy DPP MAP — persistent kernel, round 2.
// N=8192 rows, D=512, K=256. 128 blocks x 256 threads; 4 lanes per row.
// Own FN row chunk (128 floats) in registers; fn_j broadcast via padded LDS;
// cis stored transposed (cisT[n][K]) globally + own-row mirror in LDS.
// One grid barrier per step (partials + redundant final argmax, ping-pong).

#define N 8192
#define D 512
#define K 256
#define LAMBDA_REG 0.01f
#define NBLK 128
#define NTHR 256
#define ROWS 64          // rows per block
#define CH4  32          // float4s per lane chunk (128 floats)
#define GJ4  33          // padded float4 stride per chunk in lds_gj
#define CTS  260         // padded float stride per row in lds_ct

#define SCOPE __HIP_MEMORY_SCOPE_AGENT

struct __align__(8) Pick { float v; int i; };

__device__ __forceinline__ bool better(float av, int ai, float bv, int bi) {
    // first-max semantics (jnp.argmax tie-break: lowest index wins)
    return (av > bv) || (av == bv && ai < bi);
}

__device__ __forceinline__ void grid_barrier(unsigned* bar) {
    __threadfence();
    __syncthreads();
    if (threadIdx.x == 0) {
        unsigned* cnt = bar;
        unsigned* gen = bar + 1;
        unsigned g = __hip_atomic_load(gen, __ATOMIC_RELAXED, SCOPE);
        unsigned a = __hip_atomic_fetch_add(cnt, 1u, __ATOMIC_ACQ_REL, SCOPE);
        if (a == NBLK - 1) {
            __hip_atomic_store(cnt, 0u, __ATOMIC_RELAXED, SCOPE);
            __hip_atomic_fetch_add(gen, 1u, __ATOMIC_ACQ_REL, SCOPE);
        } else {
            while (__hip_atomic_load(gen, __ATOMIC_RELAXED, SCOPE) == g)
                __builtin_amdgcn_s_sleep(1);
        }
    }
    __syncthreads();
    __threadfence();
}

__global__ __launch_bounds__(NTHR, 1) void dpp_kernel(
        const float* __restrict__ F, const float* __restrict__ q,
        float* __restrict__ FN, float* __restrict__ cisT,
        Pick* __restrict__ parts, unsigned* __restrict__ bar,
        int* __restrict__ out)
{
    const int tid = threadIdx.x;
    const int blk = blockIdx.x;
    const int r   = tid >> 2;        // local row 0..63
    const int c   = tid & 3;         // D-chunk lane 0..3
    const int n   = blk * ROWS + r;  // global row

    __shared__ float4 lds_gj[4 * GJ4];     // fn_j, 4 padded chunks
    __shared__ float  lds_ct[ROWS * CTS];  // own rows' cisT mirror
    __shared__ float  lds_cj[K];           // cisT[j][0..t)
    __shared__ Pick   lds_wave[NTHR / 64];
    __shared__ Pick   lds_final;

    const float4* F4  = reinterpret_cast<const float4*>(F);
    float4*       FN4 = reinterpret_cast<float4*>(FN);

    // ---- init: load own chunk, normalize, keep in registers, write FN ----
    float4 reg[CH4];
    float  qn, dloc;
    bool   masked = false;
    {
        const float4* src = F4 + (size_t)n * (D / 4) + c * CH4;
        float ss = 0.f;
        #pragma unroll
        for (int i = 0; i < CH4; ++i) {
            float4 v = src[i]; reg[i] = v;
            ss = fmaf(v.x, v.x, ss); ss = fmaf(v.y, v.y, ss);
            ss = fmaf(v.z, v.z, ss); ss = fmaf(v.w, v.w, ss);
        }
        ss += __shfl_xor(ss, 1);
        ss += __shfl_xor(ss, 2);
        const float norm = sqrtf(ss);
        float ssn = 0.f;
        #pragma unroll
        for (int i = 0; i < CH4; ++i) {
            float4 v = reg[i];
            v.x /= norm; v.y /= norm; v.z /= norm; v.w /= norm;
            reg[i] = v;
            ssn = fmaf(v.x, v.x, ssn); ssn = fmaf(v.y, v.y, ssn);
            ssn = fmaf(v.z, v.z, ssn); ssn = fmaf(v.w, v.w, ssn);
        }
        ssn += __shfl_xor(ssn, 1);
        ssn += __shfl_xor(ssn, 2);
        float4* dst = FN4 + (size_t)n * (D / 4) + c * CH4;
        #pragma unroll
        for (int i = 0; i < CH4; ++i) dst[i] = reg[i];
        qn = q[n];
        dloc = fmaf(sqrtf(qn * qn), ssn, LAMBDA_REG);
    }

    // ---- first block-partial argmax (buffer 0) ----
    {
        float v = dloc; int idx = n;
        #pragma unroll
        for (int m = 32; m > 0; m >>= 1) {
            float ov = __shfl_xor(v, m);
            int   oi = __shfl_xor(idx, m);
            if (better(ov, oi, v, idx)) { v = ov; idx = oi; }
        }
        if ((tid & 63) == 0) { lds_wave[tid >> 6].v = v; lds_wave[tid >> 6].i = idx; }
        __syncthreads();
        if (tid == 0) {
            Pick p = lds_wave[0];
            #pragma unroll
            for (int w = 1; w < NTHR / 64; ++w) {
                Pick o = lds_wave[w];
                if (better(o.v, o.i, p.v, p.i)) p = o;
            }
            parts[blk] = p;
        }
    }
    grid_barrier(bar);

    for (int t = 0; t < K; ++t) {
        // ---- redundant final argmax over 128 partials ----
        {
            const Pick* pbuf = parts + (t & 1) * NBLK;
            if (tid < 64) {
                Pick p = pbuf[tid];
                Pick o = pbuf[tid + 64];
                if (better(o.v, o.i, p.v, p.i)) p = o;
                float v = p.v; int idx = p.i;
                #pragma unroll
                for (int m = 32; m > 0; m >>= 1) {
                    float ov = __shfl_xor(v, m);
                    int   oi = __shfl_xor(idx, m);
                    if (better(ov, oi, v, idx)) { v = ov; idx = oi; }
                }
                if (tid == 0) { lds_final.v = v; lds_final.i = idx; }
            }
            __syncthreads();
        }
        const float dj = lds_final.v;
        const int   j  = lds_final.i;

        if (blk == 0 && tid == 0) out[t] = j;
        if (t == K - 1) break;

        const float sj = sqrtf(dj);
        const float qj = q[j];

        // ---- stage fn_j (padded) and cisT[j][0..t) into LDS ----
        if (tid < 128) {
            float4 g = FN4[(size_t)j * (D / 4) + tid];
            lds_gj[(tid >> 5) * GJ4 + (tid & 31)] = g;
        }
        if (tid < t) lds_cj[tid] = cisT[(size_t)j * K + tid];
        __syncthreads();

        // ---- dot = <fn_j, fn_n> : registers x LDS, conflict-free ----
        const float4* g4 = lds_gj + c * GJ4;
        float4 a = {0.f, 0.f, 0.f, 0.f};
        #pragma unroll
        for (int i = 0; i < CH4; ++i) {
            float4 v = reg[i], g = g4[i];
            a.x = fmaf(v.x, g.x, a.x); a.y = fmaf(v.y, g.y, a.y);
            a.z = fmaf(v.z, g.z, a.z); a.w = fmaf(v.w, g.w, a.w);
        }
        float dot = (a.x + a.y) + (a.z + a.w);
        dot += __shfl_xor(dot, 1);
        dot += __shfl_xor(dot, 2);
        float Ljn = sqrtf(qj * qn) * dot;
        if (n == j) Ljn += LAMBDA_REG;

        // ---- cd = sum_tt cisT[j][tt] * cisT[n][tt], LDS-only ----
        float cd = 0.f;
        float* ctrow = lds_ct + r * CTS;
        for (int tt = c; tt < t; tt += 4)
            cd = fmaf(lds_cj[tt], ctrow[tt], cd);
        cd += __shfl_xor(cd, 1);
        cd += __shfl_xor(cd, 2);

        const float e = (Ljn - cd) / sj;
        if (c == 0) {
            cisT[(size_t)n * K + t] = e;  // global (for future j-column staging)
            ctrow[t] = e;                 // LDS mirror (own cd loop)
        }
        dloc = fmaf(-e, e, dloc);
        if (n == j) masked = true;

        __syncthreads();   // WAR: lds_wave / lds_gj / lds_cj reuse

        // ---- block-partial argmax for step t+1 ----
        {
            float v = masked ? -INFINITY : dloc; int idx = n;
            #pragma unroll
            for (int m = 32; m > 0; m >>= 1) {
                float ov = __shfl_xor(v, m);
                int   oi = __shfl_xor(idx, m);
                if (better(ov, oi, v, idx)) { v = ov; idx = oi; }
            }
            if ((tid & 63) == 0) { lds_wave[tid >> 6].v = v; lds_wave[tid >> 6].i = idx; }
            __syncthreads();
            if (tid == 0) {
                Pick p = lds_wave[0];
                #pragma unroll
                for (int w = 1; w < NTHR / 64; ++w) {
                    Pick o = lds_wave[w];
                    if (better(o.v, o.i, p.v, p.i)) p = o;
                }
                parts[((t + 1) & 1) * NBLK + blk] = p;
            }
        }
        grid_barrier(bar);
    }
}

extern "C" void kernel_launch(void* const* d_in, const int* in_sizes, int n_in,
                              void* d_out, int out_size, void* d_ws, size_t ws_size,
                              hipStream_t stream) {
    const float* F = (const float*)d_in[0];
    const float* q = (const float*)d_in[1];
    int* out = (int*)d_out;

    uint8_t* w = (uint8_t*)d_ws;
    unsigned* bar  = (unsigned*)w;
    Pick*    parts = (Pick*)(w + 256);                       // 2*NBLK*8 = 2KB
    float*   FN    = (float*)(w + 4096);                     // 16 MB
    float*   cisT  = (float*)(w + 4096 + (size_t)N * D * 4); // 8 MB
    // total ws needed ~25.2 MB (same as round 1)

    hipMemsetAsync(d_ws, 0, 256, stream);   // zero barrier state each launch
    hipLaunchKernelGGL(dpp_kernel, dim3(NBLK), dim3(NTHR), 0, stream,
                       F, q, FN, cisT, parts, bar, out);
}

// Round 3
// 6323.496 us; speedup vs baseline: 1.0487x; 1.0487x over previous
//
#include <hip/hip_runtime.h>
#include <math.h>
#include <stdint.h>

// Greedy DPP MAP — persistent kernel, round 3.
// N=8192 rows, D=512, K=256. 256 blocks x 256 threads (1 block/CU); 8 lanes/row,
// 64-float row chunk in registers (64 VGPR -> no spill, unlike round 2's 128).
// Grid sync: tagged-slot polling barrier MERGED with argmax exchange —
// each block release-stores one 8B epoch-tagged partial {v, tag|idx};
// wave 0 polls all 256 slots (relaxed atomic loads, no RMW) and reduces them.
// Ping-pong slot buffers; slots memset 0xFF per launch (stale-tag safety).
//
// ws: [256, 256+4KB) slot buffers [2][256] u64
//     [8192, +16MB)  FN   normalized features
//     [+16MB, +8MB)  cisT transposed e-rows [N][K]

#define N 8192
#define D 512
#define K 256
#define LAMBDA_REG 0.01f
#define NBLK 256
#define NTHR 256
#define ROWS 32          // rows per block
#define CH4  16          // float4s per lane chunk (64 floats)
#define CTS  264         // padded float stride for lds_ct (2-way conflicts = free)
#define SCOPE __HIP_MEMORY_SCOPE_AGENT

typedef unsigned long long u64;

struct __align__(8) Pick { float v; int i; };

__device__ __forceinline__ bool better(float av, int ai, float bv, int bi) {
    // first-max semantics (jnp.argmax tie-break: lowest index wins)
    return (av > bv) || (av == bv && ai < bi);
}

__device__ __forceinline__ u64 pack_slot(float v, int idx, int tag) {
    unsigned hi = ((unsigned)tag << 13) | (unsigned)idx;   // idx < 8192 (13 bits)
    return ((u64)hi << 32) | (u64)__float_as_uint(v);
}

__global__ __launch_bounds__(NTHR, 1) void dpp_kernel(
        const float* __restrict__ F, const float* __restrict__ q,
        float* __restrict__ FN, float* __restrict__ cisT,
        u64* __restrict__ slots, int* __restrict__ out)
{
    const int tid = threadIdx.x;
    const int blk = blockIdx.x;
    const int r   = tid >> 3;        // local row 0..31
    const int c   = tid & 7;         // chunk lane 0..7
    const int n   = blk * ROWS + r;  // global row

    __shared__ float lds_ct[ROWS * CTS];   // own rows' cisT prefix mirror
    __shared__ float lds_cj[K];            // cisT[j][0..t)
    __shared__ Pick  lds_wave[NTHR / 64];
    __shared__ Pick  lds_final;

    const float4* F4  = reinterpret_cast<const float4*>(F);
    float4*       FN4 = reinterpret_cast<float4*>(FN);

    // ---- init: load own 64-float chunk, normalize, keep in regs ----
    float4 reg[CH4];
    float  qn, dloc;
    bool   masked = false;
    {
        const float4* src = F4 + (size_t)n * (D / 4) + c * CH4;
        float ss = 0.f;
        #pragma unroll
        for (int i = 0; i < CH4; ++i) {
            float4 v = src[i]; reg[i] = v;
            ss = fmaf(v.x, v.x, ss); ss = fmaf(v.y, v.y, ss);
            ss = fmaf(v.z, v.z, ss); ss = fmaf(v.w, v.w, ss);
        }
        ss += __shfl_xor(ss, 1); ss += __shfl_xor(ss, 2); ss += __shfl_xor(ss, 4);
        const float norm = sqrtf(ss);
        float ssn = 0.f;
        #pragma unroll
        for (int i = 0; i < CH4; ++i) {
            float4 v = reg[i];
            v.x /= norm; v.y /= norm; v.z /= norm; v.w /= norm;
            reg[i] = v;
            ssn = fmaf(v.x, v.x, ssn); ssn = fmaf(v.y, v.y, ssn);
            ssn = fmaf(v.z, v.z, ssn); ssn = fmaf(v.w, v.w, ssn);
        }
        ssn += __shfl_xor(ssn, 1); ssn += __shfl_xor(ssn, 2); ssn += __shfl_xor(ssn, 4);
        float4* dst = FN4 + (size_t)n * (D / 4) + c * CH4;
        #pragma unroll
        for (int i = 0; i < CH4; ++i) dst[i] = reg[i];
        qn = q[n];
        dloc = fmaf(sqrtf(qn * qn), ssn, LAMBDA_REG);
    }

    // ---- initial block partial (tag 0, buffer 0) ----
    {
        float v = dloc; int idx = n;
        #pragma unroll
        for (int m = 32; m > 0; m >>= 1) {
            float ov = __shfl_xor(v, m);
            int   oi = __shfl_xor(idx, m);
            if (better(ov, oi, v, idx)) { v = ov; idx = oi; }
        }
        if ((tid & 63) == 0) { lds_wave[tid >> 6].v = v; lds_wave[tid >> 6].i = idx; }
        __syncthreads();              // also drains FN stores (vmcnt) per-thread
        if (tid == 0) {
            Pick p = lds_wave[0];
            #pragma unroll
            for (int w = 1; w < NTHR / 64; ++w) {
                Pick o = lds_wave[w];
                if (better(o.v, o.i, p.v, p.i)) p = o;
            }
            __threadfence();          // release: FN + partial visible device-wide
            __hip_atomic_store(&slots[blk], pack_slot(p.v, p.i, 0),
                               __ATOMIC_RELAXED, SCOPE);
        }
    }

    for (int t = 0; t < K; ++t) {
        // ---- poll barrier + final argmax (wave 0) ----
        if (tid < 64) {
            const u64* pb = slots + (t & 1) * NBLK;
            const int s = tid * 4;
            u64 x0, x1, x2, x3;
            const unsigned want = (unsigned)t;
            while (true) {
                x0 = __hip_atomic_load(pb + s,     __ATOMIC_RELAXED, SCOPE);
                x1 = __hip_atomic_load(pb + s + 1, __ATOMIC_RELAXED, SCOPE);
                x2 = __hip_atomic_load(pb + s + 2, __ATOMIC_RELAXED, SCOPE);
                x3 = __hip_atomic_load(pb + s + 3, __ATOMIC_RELAXED, SCOPE);
                bool ok = ((unsigned)(x0 >> 45) == want) &&
                          ((unsigned)(x1 >> 45) == want) &&
                          ((unsigned)(x2 >> 45) == want) &&
                          ((unsigned)(x3 >> 45) == want);
                if (__all(ok)) break;
                __builtin_amdgcn_s_sleep(2);
            }
            float v = __uint_as_float((unsigned)x0);
            int idx = (int)((x0 >> 32) & 8191u);
            {
                float w = __uint_as_float((unsigned)x1); int k1 = (int)((x1 >> 32) & 8191u);
                if (better(w, k1, v, idx)) { v = w; idx = k1; }
                w = __uint_as_float((unsigned)x2); k1 = (int)((x2 >> 32) & 8191u);
                if (better(w, k1, v, idx)) { v = w; idx = k1; }
                w = __uint_as_float((unsigned)x3); k1 = (int)((x3 >> 32) & 8191u);
                if (better(w, k1, v, idx)) { v = w; idx = k1; }
            }
            #pragma unroll
            for (int m = 32; m > 0; m >>= 1) {
                float ov = __shfl_xor(v, m);
                int   oi = __shfl_xor(idx, m);
                if (better(ov, oi, v, idx)) { v = ov; idx = oi; }
            }
            if (tid == 0) { lds_final.v = v; lds_final.i = idx; }
        }
        __syncthreads();
        __threadfence();              // acquire side
        const float dj = lds_final.v;
        const int   j  = lds_final.i;

        if (blk == 0 && tid == 0) out[t] = j;
        if (t == K - 1) break;

        const float sj = sqrtf(dj);
        const float qj = q[j];

        // ---- stage cisT[j][0..t) into LDS (one coalesced round) ----
        if (tid < t) lds_cj[tid] = cisT[(size_t)j * K + tid];

        // ---- dot = <fn_j, fn_n> : direct global fn_j (L1-broadcast) x regs ----
        const float4* gj = FN4 + (size_t)j * (D / 4) + c * CH4;
        float4 a = {0.f, 0.f, 0.f, 0.f};
        #pragma unroll
        for (int i = 0; i < CH4; ++i) {
            float4 v = reg[i], g = gj[i];
            a.x = fmaf(v.x, g.x, a.x); a.y = fmaf(v.y, g.y, a.y);
            a.z = fmaf(v.z, g.z, a.z); a.w = fmaf(v.w, g.w, a.w);
        }
        float dot = (a.x + a.y) + (a.z + a.w);
        dot += __shfl_xor(dot, 1); dot += __shfl_xor(dot, 2); dot += __shfl_xor(dot, 4);
        float Ljn = sqrtf(qj * qn) * dot;
        if (n == j) Ljn += LAMBDA_REG;

        __syncthreads();              // lds_cj ready

        // ---- cd = sum_tt cisT[j][tt] * cisT[n][tt] : LDS x LDS ----
        float cd = 0.f;
        float* ctrow = lds_ct + r * CTS;
        #pragma unroll 4
        for (int tt = c; tt < t; tt += 8)
            cd = fmaf(lds_cj[tt], ctrow[tt], cd);
        cd += __shfl_xor(cd, 1); cd += __shfl_xor(cd, 2); cd += __shfl_xor(cd, 4);

        const float e = (Ljn - cd) / sj;
        if (c == 0) {
            cisT[(size_t)n * K + t] = e;
            ctrow[t] = e;
        }
        dloc = fmaf(-e, e, dloc);
        if (n == j) masked = true;

        // ---- block partial for step t+1 ----
        {
            float v = masked ? -INFINITY : dloc; int idx = n;
            #pragma unroll
            for (int m = 32; m > 0; m >>= 1) {
                float ov = __shfl_xor(v, m);
                int   oi = __shfl_xor(idx, m);
                if (better(ov, oi, v, idx)) { v = ov; idx = oi; }
            }
            if ((tid & 63) == 0) { lds_wave[tid >> 6].v = v; lds_wave[tid >> 6].i = idx; }
            __syncthreads();          // drains cisT store; protects lds_wave/lds_cj
            if (tid == 0) {
                Pick p = lds_wave[0];
                #pragma unroll
                for (int w = 1; w < NTHR / 64; ++w) {
                    Pick o = lds_wave[w];
                    if (better(o.v, o.i, p.v, p.i)) p = o;
                }
                __threadfence();      // release: cisT row + partial visible
                __hip_atomic_store(&slots[((t + 1) & 1) * NBLK + blk],
                                   pack_slot(p.v, p.i, t + 1),
                                   __ATOMIC_RELAXED, SCOPE);
            }
        }
    }
}

extern "C" void kernel_launch(void* const* d_in, const int* in_sizes, int n_in,
                              void* d_out, int out_size, void* d_ws, size_t ws_size,
                              hipStream_t stream) {
    const float* F = (const float*)d_in[0];
    const float* q = (const float*)d_in[1];
    int* out = (int*)d_out;

    uint8_t* w = (uint8_t*)d_ws;
    u64*   slots = (u64*)(w + 256);                       // 2*256*8 = 4 KB
    float* FN    = (float*)(w + 8192);                    // 16 MB
    float* cisT  = (float*)(w + 8192 + (size_t)N * D * 4); // 8 MB

    // invalidate slot tags each launch (graph replays reuse ws)
    hipMemsetAsync((void*)(w + 256), 0xFF, 4096, stream);
    hipLaunchKernelGGL(dpp_kernel, dim3(NBLK), dim3(NTHR), 0, stream,
                       F, q, FN, cisT, slots, out);
}

// Round 4
// 1910.325 us; speedup vs baseline: 3.4715x; 3.3102x over previous
//
#include <hip/hip_runtime.h>
#include <math.h>
#include <stdint.h>

// Greedy DPP MAP — persistent kernel, round 4.
// N=8192, D=512, K=256. 256 blocks x 256 threads (1 block/CU); 8 lanes/row.
// NO per-thread arrays (rounds 2/3 spilled); NO __threadfence (agent fences
// triggered per-step cache maintenance = the fixed 20+ us/step cost).
// Own FN rows + own cis prefix live in LDS. Cross-block data moves through
// the LLC via explicit coherent ops:
//   - fn_j / cisT[j] prefix: global_load ... sc0 sc1 (bypass L1/L2, read LLC)
//   - cisT per-step writes:  global_store ... sc0 sc1 (LLC-direct, L2 stays clean)
//   - slot exchange: relaxed atomic poll + one RELEASE atomic store per block
// LDS bank layout: row stride 560 floats, chunk stride 68 floats -> every
// 16-lane b128 group covers 8 bank-quads exactly 2-way (free).

#define N 8192
#define D 512
#define K 256
#define LAMBDA_REG 0.01f
#define NBLK 256
#define NTHR 256
#define ROWS 32          // rows per block
#define RS   560         // floats per row in lds_fn (8 chunks * 68 + 16)
#define CS   68          // floats per 64-float chunk (64 + 4 pad)
#define CTS  264         // floats per row in lds_ct
#define SCOPE __HIP_MEMORY_SCOPE_AGENT

typedef unsigned long long u64;

struct __align__(8) Pick { float v; int i; };

__device__ __forceinline__ bool better(float av, int ai, float bv, int bi) {
    // first-max semantics (jnp.argmax tie-break: lowest index wins)
    return (av > bv) || (av == bv && ai < bi);
}

__device__ __forceinline__ u64 pack_slot(float v, int idx, int tag) {
    unsigned hi = ((unsigned)tag << 13) | (unsigned)idx;   // idx < 8192
    return ((u64)hi << 32) | (u64)__float_as_uint(v);
}

__global__ __launch_bounds__(NTHR, 1) void dpp_kernel(
        const float* __restrict__ F, const float* __restrict__ q,
        float* __restrict__ FN, float* __restrict__ cisT,
        u64* __restrict__ slots, int* __restrict__ out)
{
    const int tid = threadIdx.x;
    const int blk = blockIdx.x;
    const int r   = tid >> 3;        // local row 0..31
    const int c   = tid & 7;         // chunk lane 0..7
    const int n   = blk * ROWS + r;  // global row

    __shared__ __align__(16) float lds_fn[ROWS * RS];   // 71,680 B own FN rows
    __shared__ __align__(16) float lds_ct[ROWS * CTS];  // 33,792 B own cis prefix
    __shared__ __align__(16) float lds_gj[8 * CS];      //  2,176 B fn_j staged
    __shared__ __align__(16) float lds_cj[K];           //  1,024 B cisT[j][0..t)
    __shared__ Pick lds_wave[NTHR / 64];
    __shared__ Pick lds_final;

    const float4* F4  = reinterpret_cast<const float4*>(F);
    float4*       FN4 = reinterpret_cast<float4*>(FN);

    // ---- init: load own row, normalize (LDS as scratch, no reg arrays) ----
    float dloc, qn;
    bool  masked = false;
    {
        const float4* src = F4 + (size_t)n * (D / 4) + c * 16;
        float* frow = &lds_fn[r * RS + c * CS];
        float ss = 0.f;
        #pragma unroll
        for (int i = 0; i < 16; ++i) {
            float4 v = src[i];
            *reinterpret_cast<float4*>(frow + 4 * i) = v;
            ss = fmaf(v.x, v.x, ss); ss = fmaf(v.y, v.y, ss);
            ss = fmaf(v.z, v.z, ss); ss = fmaf(v.w, v.w, ss);
        }
        ss += __shfl_xor(ss, 1); ss += __shfl_xor(ss, 2); ss += __shfl_xor(ss, 4);
        const float norm = sqrtf(ss);
        float4* dst = FN4 + (size_t)n * (D / 4) + c * 16;
        float ssn = 0.f;
        #pragma unroll
        for (int i = 0; i < 16; ++i) {
            float4 v = *reinterpret_cast<float4*>(frow + 4 * i);
            v.x /= norm; v.y /= norm; v.z /= norm; v.w /= norm;
            *reinterpret_cast<float4*>(frow + 4 * i) = v;
            dst[i] = v;   // normal store; flushed by init RELEASE below
            ssn = fmaf(v.x, v.x, ssn); ssn = fmaf(v.y, v.y, ssn);
            ssn = fmaf(v.z, v.z, ssn); ssn = fmaf(v.w, v.w, ssn);
        }
        ssn += __shfl_xor(ssn, 1); ssn += __shfl_xor(ssn, 2); ssn += __shfl_xor(ssn, 4);
        qn = q[n];
        dloc = fmaf(sqrtf(qn * qn), ssn, LAMBDA_REG);
    }

    // ---- initial block partial (tag 0, buffer 0) ----
    {
        float v = dloc; int idx = n;
        #pragma unroll
        for (int m = 32; m > 0; m >>= 1) {
            float ov = __shfl_xor(v, m);
            int   oi = __shfl_xor(idx, m);
            if (better(ov, oi, v, idx)) { v = ov; idx = oi; }
        }
        if ((tid & 63) == 0) { lds_wave[tid >> 6].v = v; lds_wave[tid >> 6].i = idx; }
        __syncthreads();              // all waves' FN stores drained (pre-barrier waitcnt)
        if (tid == 0) {
            Pick p = lds_wave[0];
            #pragma unroll
            for (int w = 1; w < NTHR / 64; ++w) {
                Pick o = lds_wave[w];
                if (better(o.v, o.i, p.v, p.i)) p = o;
            }
            __hip_atomic_store(&slots[blk], pack_slot(p.v, p.i, 0),
                               __ATOMIC_RELEASE, SCOPE);   // flushes dirty FN to LLC
        }
    }

    for (int t = 0; t < K; ++t) {
        // ---- A: poll barrier + final argmax (wave 0 only) ----
        if (tid < 64) {
            const u64* pb = slots + (t & 1) * NBLK;
            const int s = tid * 4;
            u64 x0, x1, x2, x3;
            const unsigned want = (unsigned)t;
            while (true) {
                x0 = __hip_atomic_load(pb + s,     __ATOMIC_RELAXED, SCOPE);
                x1 = __hip_atomic_load(pb + s + 1, __ATOMIC_RELAXED, SCOPE);
                x2 = __hip_atomic_load(pb + s + 2, __ATOMIC_RELAXED, SCOPE);
                x3 = __hip_atomic_load(pb + s + 3, __ATOMIC_RELAXED, SCOPE);
                bool ok = ((unsigned)(x0 >> 45) == want) &&
                          ((unsigned)(x1 >> 45) == want) &&
                          ((unsigned)(x2 >> 45) == want) &&
                          ((unsigned)(x3 >> 45) == want);
                if (__all(ok)) break;
                __builtin_amdgcn_s_sleep(1);
            }
            asm volatile("" ::: "memory");   // no hoisting data reads above poll
            float v = __uint_as_float((unsigned)x0);
            int idx = (int)((x0 >> 32) & 8191u);
            {
                float w = __uint_as_float((unsigned)x1); int k1 = (int)((x1 >> 32) & 8191u);
                if (better(w, k1, v, idx)) { v = w; idx = k1; }
                w = __uint_as_float((unsigned)x2); k1 = (int)((x2 >> 32) & 8191u);
                if (better(w, k1, v, idx)) { v = w; idx = k1; }
                w = __uint_as_float((unsigned)x3); k1 = (int)((x3 >> 32) & 8191u);
                if (better(w, k1, v, idx)) { v = w; idx = k1; }
            }
            #pragma unroll
            for (int m = 32; m > 0; m >>= 1) {
                float ov = __shfl_xor(v, m);
                int   oi = __shfl_xor(idx, m);
                if (better(ov, oi, v, idx)) { v = ov; idx = oi; }
            }
            if (tid == 0) { lds_final.v = v; lds_final.i = idx; }
        }
        __syncthreads();                              // S1
        const float dj = lds_final.v;
        const int   j  = lds_final.i;

        if (blk == 0 && tid == 0) out[t] = j;
        if (t == K - 1) break;

        const float sj = sqrtf(dj);
        const float qj = q[j];

        // ---- B: coherent bypass loads of fn_j + cisT[j][0..t), stage to LDS ----
        float4 gv;
        float  cv;
        if (tid < 128) {
            const float4* gp = FN4 + (size_t)j * (D / 4) + tid;
            asm volatile("global_load_dwordx4 %0, %1, off sc0 sc1"
                         : "=v"(gv) : "v"(gp));
        }
        if (tid < t) {
            const float* cp = cisT + (size_t)j * K + tid;
            asm volatile("global_load_dword %0, %1, off sc0 sc1"
                         : "=v"(cv) : "v"(cp));
        }
        asm volatile("s_waitcnt vmcnt(0)" ::: "memory");
        __builtin_amdgcn_sched_barrier(0);
        if (tid < 128) {
            // float4 idx tid -> chunk tid>>4, quad (tid&15)
            *reinterpret_cast<float4*>(&lds_gj[(tid >> 4) * CS + (tid & 15) * 4]) = gv;
        }
        if (tid < t) lds_cj[tid] = cv;
        __syncthreads();                              // S2

        // ---- C: dot (LDS x LDS, 2-way max), cd, e, updates ----
        const float* frow = &lds_fn[r * RS + c * CS];
        const float* grow = &lds_gj[c * CS];
        float4 a = {0.f, 0.f, 0.f, 0.f};
        #pragma unroll
        for (int i = 0; i < 16; ++i) {
            float4 v = *reinterpret_cast<const float4*>(frow + 4 * i);
            float4 g = *reinterpret_cast<const float4*>(grow + 4 * i);
            a.x = fmaf(v.x, g.x, a.x); a.y = fmaf(v.y, g.y, a.y);
            a.z = fmaf(v.z, g.z, a.z); a.w = fmaf(v.w, g.w, a.w);
        }
        float dot = (a.x + a.y) + (a.z + a.w);
        dot += __shfl_xor(dot, 1); dot += __shfl_xor(dot, 2); dot += __shfl_xor(dot, 4);
        float Ljn = sqrtf(qj * qn) * dot;
        if (n == j) Ljn += LAMBDA_REG;

        float cd = 0.f;
        const float* ctrow = &lds_ct[r * CTS];
        for (int tt = c; tt < t; tt += 8)
            cd = fmaf(lds_cj[tt], ctrow[tt], cd);
        cd += __shfl_xor(cd, 1); cd += __shfl_xor(cd, 2); cd += __shfl_xor(cd, 4);

        const float e = (Ljn - cd) / sj;
        if (c == 0) {
            lds_ct[r * CTS + t] = e;
            const float* ep = cisT + (size_t)n * K + t;
            asm volatile("global_store_dword %0, %1, off sc0 sc1"
                         :: "v"(ep), "v"(e) : "memory");
        }
        dloc = fmaf(-e, e, dloc);
        if (n == j) masked = true;

        // ---- block partial for step t+1 ----
        {
            float v = masked ? -INFINITY : dloc; int idx = n;
            #pragma unroll
            for (int m = 32; m > 0; m >>= 1) {
                float ov = __shfl_xor(v, m);
                int   oi = __shfl_xor(idx, m);
                if (better(ov, oi, v, idx)) { v = ov; idx = oi; }
            }
            if ((tid & 63) == 0) { lds_wave[tid >> 6].v = v; lds_wave[tid >> 6].i = idx; }
        }
        asm volatile("s_waitcnt vmcnt(0)" ::: "memory");  // drain asm e-store
        __syncthreads();                              // S3
        if (tid == 0) {
            Pick p = lds_wave[0];
            #pragma unroll
            for (int w = 1; w < NTHR / 64; ++w) {
                Pick o = lds_wave[w];
                if (better(o.v, o.i, p.v, p.i)) p = o;
            }
            __hip_atomic_store(&slots[((t + 1) & 1) * NBLK + blk],
                               pack_slot(p.v, p.i, t + 1),
                               __ATOMIC_RELEASE, SCOPE);  // L2 clean -> cheap
        }
    }
}

extern "C" void kernel_launch(void* const* d_in, const int* in_sizes, int n_in,
                              void* d_out, int out_size, void* d_ws, size_t ws_size,
                              hipStream_t stream) {
    const float* F = (const float*)d_in[0];
    const float* q = (const float*)d_in[1];
    int* out = (int*)d_out;

    uint8_t* w = (uint8_t*)d_ws;
    u64*   slots = (u64*)(w + 256);                        // 2*256*8 = 4 KB
    float* FN    = (float*)(w + 8192);                     // 16 MB
    float* cisT  = (float*)(w + 8192 + (size_t)N * D * 4); // 8 MB

    // invalidate slot tags each launch (graph replays reuse ws)
    hipMemsetAsync((void*)(w + 256), 0xFF, 4096, stream);
    hipLaunchKernelGGL(dpp_kernel, dim3(NBLK), dim3(NTHR), 0, stream,
                       F, q, FN, cisT, slots, out);
}

// Round 6
// 1370.207 us; speedup vs baseline: 4.8400x; 1.3942x over previous
//
#include <hip/hip_runtime.h>
#include <math.h>
#include <stdint.h>

// Greedy DPP MAP — persistent kernel, round 6 (round 5 + asm-constraint fix).
// N=8192, D=512, K=256. 256 blocks x 256 threads (1 block/CU); 8 lanes/row.
// ZERO fences / ordered atomics: every cross-block byte (FN rows, cisT rows,
// slot messages) moves via explicit sc0+sc1 bypass ops serviced at the LLC;
// ordering = per-thread s_waitcnt vmcnt(0) + s_barrier before each block's
// slot publish (plain relaxed 8B bypass store). Removes the per-step L2
// writeback walk the round-4 RELEASE atomic put on the critical path.
// Fix vs round 5: asm vector operands use ext_vector_type (native vector),
// not HIP float4 struct (struct inputs are passed indirectly -> compile error).

#define N 8192
#define D 512
#define K 256
#define LAMBDA_REG 0.01f
#define NBLK 256
#define NTHR 256
#define ROWS 32          // rows per block
#define RS   560         // floats per row in lds_fn
#define CS   68          // floats per 64-float chunk (64 + 4 pad)
#define CTS  264         // floats per row in lds_ct
#define SCOPE __HIP_MEMORY_SCOPE_AGENT

typedef unsigned long long u64;
typedef float f32x4 __attribute__((ext_vector_type(4)));

struct __align__(8) Pick { float v; int i; };

__device__ __forceinline__ bool better(float av, int ai, float bv, int bi) {
    // first-max semantics (jnp.argmax tie-break: lowest index wins)
    return (av > bv) || (av == bv && ai < bi);
}

__device__ __forceinline__ u64 pack_slot(float v, int idx, int tag) {
    unsigned hi = ((unsigned)tag << 13) | (unsigned)idx;   // idx < 8192
    return ((u64)hi << 32) | (u64)__float_as_uint(v);
}

__device__ __forceinline__ void bypass_store_u64(u64* p, u64 v) {
    asm volatile("global_store_dwordx2 %0, %1, off sc0 sc1"
                 :: "v"(p), "v"(v) : "memory");
}

__device__ __forceinline__ void bypass_store_f32x4(const f32x4* p, f32x4 v) {
    asm volatile("global_store_dwordx4 %0, %1, off sc0 sc1"
                 :: "v"(p), "v"(v) : "memory");
}

__device__ __forceinline__ f32x4 bypass_load_f32x4(const f32x4* p) {
    f32x4 r;
    asm volatile("global_load_dwordx4 %0, %1, off sc0 sc1"
                 : "=v"(r) : "v"(p));
    return r;
}

__global__ __launch_bounds__(NTHR, 1) void dpp_kernel(
        const float* __restrict__ F, const float* __restrict__ q,
        float* __restrict__ FN, float* __restrict__ cisT,
        u64* __restrict__ slots, int* __restrict__ out)
{
    const int tid = threadIdx.x;
    const int blk = blockIdx.x;
    const int r   = tid >> 3;        // local row 0..31
    const int c   = tid & 7;         // chunk lane 0..7
    const int n   = blk * ROWS + r;  // global row

    __shared__ __align__(16) float lds_fn[ROWS * RS];   // own FN rows
    __shared__ __align__(16) float lds_ct[ROWS * CTS];  // own cis prefix
    __shared__ __align__(16) float lds_gj[8 * CS];      // fn_j staged
    __shared__ __align__(16) float lds_cj[K];           // cisT[j][0..t)
    __shared__ Pick lds_wave[NTHR / 64];
    __shared__ Pick lds_final;

    const f32x4* F4  = reinterpret_cast<const f32x4*>(F);
    f32x4*       FN4 = reinterpret_cast<f32x4*>(FN);

    // ---- init: load own row, normalize; FN written via LLC-bypass stores ----
    float dloc, qn;
    bool  masked = false;
    {
        const f32x4* src = F4 + (size_t)n * (D / 4) + c * 16;
        float* frow = &lds_fn[r * RS + c * CS];
        float ss = 0.f;
        #pragma unroll
        for (int i = 0; i < 16; ++i) {
            f32x4 v = src[i];
            *reinterpret_cast<f32x4*>(frow + 4 * i) = v;
            ss = fmaf(v.x, v.x, ss); ss = fmaf(v.y, v.y, ss);
            ss = fmaf(v.z, v.z, ss); ss = fmaf(v.w, v.w, ss);
        }
        ss += __shfl_xor(ss, 1); ss += __shfl_xor(ss, 2); ss += __shfl_xor(ss, 4);
        const float norm = sqrtf(ss);
        f32x4* dst = FN4 + (size_t)n * (D / 4) + c * 16;
        float ssn = 0.f;
        #pragma unroll
        for (int i = 0; i < 16; ++i) {
            f32x4 v = *reinterpret_cast<f32x4*>(frow + 4 * i);
            v.x /= norm; v.y /= norm; v.z /= norm; v.w /= norm;
            *reinterpret_cast<f32x4*>(frow + 4 * i) = v;
            bypass_store_f32x4(dst + i, v);
            ssn = fmaf(v.x, v.x, ssn); ssn = fmaf(v.y, v.y, ssn);
            ssn = fmaf(v.z, v.z, ssn); ssn = fmaf(v.w, v.w, ssn);
        }
        ssn += __shfl_xor(ssn, 1); ssn += __shfl_xor(ssn, 2); ssn += __shfl_xor(ssn, 4);
        qn = q[n];
        dloc = fmaf(sqrtf(qn * qn), ssn, LAMBDA_REG);
    }

    // ---- initial block partial (tag 0, buffer 0) ----
    {
        float v = dloc; int idx = n;
        #pragma unroll
        for (int m = 32; m > 0; m >>= 1) {
            float ov = __shfl_xor(v, m);
            int   oi = __shfl_xor(idx, m);
            if (better(ov, oi, v, idx)) { v = ov; idx = oi; }
        }
        if ((tid & 63) == 0) { lds_wave[tid >> 6].v = v; lds_wave[tid >> 6].i = idx; }
        asm volatile("s_waitcnt vmcnt(0)" ::: "memory");  // own FN stores at LLC
        __syncthreads();                                  // all threads drained
        if (tid == 0) {
            Pick p = lds_wave[0];
            #pragma unroll
            for (int w = 1; w < NTHR / 64; ++w) {
                Pick o = lds_wave[w];
                if (better(o.v, o.i, p.v, p.i)) p = o;
            }
            bypass_store_u64(&slots[blk], pack_slot(p.v, p.i, 0));
        }
    }

    for (int t = 0; t < K; ++t) {
        // ---- A: poll barrier + final argmax (wave 0 only) ----
        if (tid < 64) {
            const u64* pb = slots + (t & 1) * NBLK;
            const int s = tid * 4;
            u64 x0, x1, x2, x3;
            const unsigned want = (unsigned)t;
            while (true) {
                x0 = __hip_atomic_load(pb + s,     __ATOMIC_RELAXED, SCOPE);
                x1 = __hip_atomic_load(pb + s + 1, __ATOMIC_RELAXED, SCOPE);
                x2 = __hip_atomic_load(pb + s + 2, __ATOMIC_RELAXED, SCOPE);
                x3 = __hip_atomic_load(pb + s + 3, __ATOMIC_RELAXED, SCOPE);
                bool ok = ((unsigned)(x0 >> 45) == want) &&
                          ((unsigned)(x1 >> 45) == want) &&
                          ((unsigned)(x2 >> 45) == want) &&
                          ((unsigned)(x3 >> 45) == want);
                if (__all(ok)) break;
                __builtin_amdgcn_s_sleep(1);
            }
            asm volatile("" ::: "memory");
            float v = __uint_as_float((unsigned)x0);
            int idx = (int)((x0 >> 32) & 8191u);
            {
                float w = __uint_as_float((unsigned)x1); int k1 = (int)((x1 >> 32) & 8191u);
                if (better(w, k1, v, idx)) { v = w; idx = k1; }
                w = __uint_as_float((unsigned)x2); k1 = (int)((x2 >> 32) & 8191u);
                if (better(w, k1, v, idx)) { v = w; idx = k1; }
                w = __uint_as_float((unsigned)x3); k1 = (int)((x3 >> 32) & 8191u);
                if (better(w, k1, v, idx)) { v = w; idx = k1; }
            }
            #pragma unroll
            for (int m = 32; m > 0; m >>= 1) {
                float ov = __shfl_xor(v, m);
                int   oi = __shfl_xor(idx, m);
                if (better(ov, oi, v, idx)) { v = ov; idx = oi; }
            }
            if (tid == 0) { lds_final.v = v; lds_final.i = idx; }
        }
        __syncthreads();                              // S1
        const float dj = lds_final.v;
        const int   j  = lds_final.i;

        if (blk == 0 && tid == 0) out[t] = j;
        if (t == K - 1) break;

        const float sj = sqrtf(dj);
        const float qj = q[j];

        // ---- B: bypass loads of fn_j + cisT[j][0..t), stage to LDS ----
        f32x4 gv;
        float cv;
        if (tid < 128) {
            gv = bypass_load_f32x4(FN4 + (size_t)j * (D / 4) + tid);
        }
        if (tid < t) {
            const float* cp = cisT + (size_t)j * K + tid;
            asm volatile("global_load_dword %0, %1, off sc0 sc1"
                         : "=v"(cv) : "v"(cp));
        }
        asm volatile("s_waitcnt vmcnt(0)" ::: "memory");
        __builtin_amdgcn_sched_barrier(0);
        if (tid < 128) {
            *reinterpret_cast<f32x4*>(&lds_gj[(tid >> 4) * CS + (tid & 15) * 4]) = gv;
        }
        if (tid < t) lds_cj[tid] = cv;
        __syncthreads();                              // S2

        // ---- C: dot (LDS x LDS), cd, e, updates ----
        const float* frow = &lds_fn[r * RS + c * CS];
        const float* grow = &lds_gj[c * CS];
        f32x4 a = {0.f, 0.f, 0.f, 0.f};
        #pragma unroll
        for (int i = 0; i < 16; ++i) {
            f32x4 v = *reinterpret_cast<const f32x4*>(frow + 4 * i);
            f32x4 g = *reinterpret_cast<const f32x4*>(grow + 4 * i);
            a.x = fmaf(v.x, g.x, a.x); a.y = fmaf(v.y, g.y, a.y);
            a.z = fmaf(v.z, g.z, a.z); a.w = fmaf(v.w, g.w, a.w);
        }
        float dot = (a.x + a.y) + (a.z + a.w);
        dot += __shfl_xor(dot, 1); dot += __shfl_xor(dot, 2); dot += __shfl_xor(dot, 4);
        float Ljn = sqrtf(qj * qn) * dot;
        if (n == j) Ljn += LAMBDA_REG;

        float cd = 0.f;
        const float* ctrow = &lds_ct[r * CTS];
        for (int tt = c; tt < t; tt += 8)
            cd = fmaf(lds_cj[tt], ctrow[tt], cd);
        cd += __shfl_xor(cd, 1); cd += __shfl_xor(cd, 2); cd += __shfl_xor(cd, 4);

        const float e = (Ljn - cd) / sj;
        if (c == 0) {
            lds_ct[r * CTS + t] = e;
            const float* ep = cisT + (size_t)n * K + t;
            asm volatile("global_store_dword %0, %1, off sc0 sc1"
                         :: "v"(ep), "v"(e) : "memory");
        }
        dloc = fmaf(-e, e, dloc);
        if (n == j) masked = true;

        // ---- block partial for step t+1; publish via plain bypass store ----
        {
            float v = masked ? -INFINITY : dloc; int idx = n;
            #pragma unroll
            for (int m = 32; m > 0; m >>= 1) {
                float ov = __shfl_xor(v, m);
                int   oi = __shfl_xor(idx, m);
                if (better(ov, oi, v, idx)) { v = ov; idx = oi; }
            }
            if ((tid & 63) == 0) { lds_wave[tid >> 6].v = v; lds_wave[tid >> 6].i = idx; }
        }
        asm volatile("s_waitcnt vmcnt(0)" ::: "memory");  // e-store ack'd at LLC
        __syncthreads();                              // S3: whole block drained
        if (tid == 0) {
            Pick p = lds_wave[0];
            #pragma unroll
            for (int w = 1; w < NTHR / 64; ++w) {
                Pick o = lds_wave[w];
                if (better(o.v, o.i, p.v, p.i)) p = o;
            }
            bypass_store_u64(&slots[((t + 1) & 1) * NBLK + blk],
                             pack_slot(p.v, p.i, t + 1));
        }
    }
}

extern "C" void kernel_launch(void* const* d_in, const int* in_sizes, int n_in,
                              void* d_out, int out_size, void* d_ws, size_t ws_size,
                              hipStream_t stream) {
    const float* F = (const float*)d_in[0];
    const float* q = (const float*)d_in[1];
    int* out = (int*)d_out;

    uint8_t* w = (uint8_t*)d_ws;
    u64*   slots = (u64*)(w + 256);                        // 2*256*8 = 4 KB
    float* FN    = (float*)(w + 8192);                     // 16 MB
    float* cisT  = (float*)(w + 8192 + (size_t)N * D * 4); // 8 MB

    // invalidate slot tags each launch (graph replays reuse ws)
    hipMemsetAsync((void*)(w + 256), 0xFF, 4096, stream);
    hipLaunchKernelGGL(dpp_kernel, dim3(NBLK), dim3(NTHR), 0, stream,
                       F, q, FN, cisT, slots, out);
}

// Round 7
// 1289.347 us; speedup vs baseline: 5.1435x; 1.0627x over previous
//
#include <hip/hip_runtime.h>
#include <math.h>
#include <stdint.h>

// Greedy DPP MAP — persistent kernel, round 7.
// N=8192, D=512, K=256. 256 blocks x 256 threads (1 block/CU); 8 lanes/row.
// vs round 6:
//  (a) fn_j / cisT[j] prefix read with PLAIN CACHED loads (L1/L2). Safe:
//      dispatch-begin acquire invalidates caches; FN is write-once (bypass)
//      before first read; each cisT row is read exactly once (on win) after
//      all its writes drained to MALL. 32 blocks/XCD now hit local L2 instead
//      of 256 blocks queueing on the same 32 MALL lines.
//  (b) two-level relay argmax: blocks 0..7 poll 32 base slots each and
//      publish a group winner to 8 relay slots (64B apart); everyone polls
//      only the 8 relay lines. Kills the 256-wave slot-poll congestion.
// e-stores / FN-init stores / slot publishes remain sc0+sc1 bypass (churning
// cross-XCD data must live at the MALL). No fences / ordered atomics at all.

#define N 8192
#define D 512
#define K 256
#define LAMBDA_REG 0.01f
#define NBLK 256
#define NTHR 256
#define ROWS 32          // rows per block
#define RS   560         // floats per row in lds_fn
#define CS   68          // floats per 64-float chunk (64 + 4 pad)
#define CTS  264         // floats per row in lds_ct
#define NRELAY 8
#define GRP  32          // base slots per relay
#define SCOPE __HIP_MEMORY_SCOPE_AGENT

typedef unsigned long long u64;
typedef float f32x4 __attribute__((ext_vector_type(4)));

struct __align__(8) Pick { float v; int i; };

__device__ __forceinline__ bool better(float av, int ai, float bv, int bi) {
    // first-max semantics (jnp.argmax tie-break: lowest index wins)
    return (av > bv) || (av == bv && ai < bi);
}

__device__ __forceinline__ u64 pack_slot(float v, int idx, int tag) {
    unsigned hi = ((unsigned)tag << 13) | (unsigned)idx;   // idx < 8192
    return ((u64)hi << 32) | (u64)__float_as_uint(v);
}

__device__ __forceinline__ void bypass_store_u64(u64* p, u64 v) {
    asm volatile("global_store_dwordx2 %0, %1, off sc0 sc1"
                 :: "v"(p), "v"(v) : "memory");
}

__device__ __forceinline__ void bypass_store_f32x4(const f32x4* p, f32x4 v) {
    asm volatile("global_store_dwordx4 %0, %1, off sc0 sc1"
                 :: "v"(p), "v"(v) : "memory");
}

__global__ __launch_bounds__(NTHR, 1) void dpp_kernel(
        const float* __restrict__ F, const float* __restrict__ q,
        float* __restrict__ FN, float* __restrict__ cisT,
        u64* __restrict__ slots, u64* __restrict__ relay,
        int* __restrict__ out)
{
    const int tid = threadIdx.x;
    const int blk = blockIdx.x;
    const int r   = tid >> 3;        // local row 0..31
    const int c   = tid & 7;         // chunk lane 0..7
    const int n   = blk * ROWS + r;  // global row
    const bool isRelay = (blk < NRELAY);

    __shared__ __align__(16) float lds_fn[ROWS * RS];   // own FN rows
    __shared__ __align__(16) float lds_ct[ROWS * CTS];  // own cis prefix
    __shared__ __align__(16) float lds_gj[8 * CS];      // fn_j staged
    __shared__ __align__(16) float lds_cj[K];           // cisT[j][0..t)
    __shared__ Pick lds_wave[NTHR / 64];
    __shared__ Pick lds_final;

    const f32x4* F4  = reinterpret_cast<const f32x4*>(F);
    f32x4*       FN4 = reinterpret_cast<f32x4*>(FN);

    // ---- init: load own row, normalize; FN written via LLC-bypass stores ----
    float dloc, qn;
    bool  masked = false;
    {
        const f32x4* src = F4 + (size_t)n * (D / 4) + c * 16;
        float* frow = &lds_fn[r * RS + c * CS];
        float ss = 0.f;
        #pragma unroll
        for (int i = 0; i < 16; ++i) {
            f32x4 v = src[i];
            *reinterpret_cast<f32x4*>(frow + 4 * i) = v;
            ss = fmaf(v.x, v.x, ss); ss = fmaf(v.y, v.y, ss);
            ss = fmaf(v.z, v.z, ss); ss = fmaf(v.w, v.w, ss);
        }
        ss += __shfl_xor(ss, 1); ss += __shfl_xor(ss, 2); ss += __shfl_xor(ss, 4);
        const float norm = sqrtf(ss);
        f32x4* dst = FN4 + (size_t)n * (D / 4) + c * 16;
        float ssn = 0.f;
        #pragma unroll
        for (int i = 0; i < 16; ++i) {
            f32x4 v = *reinterpret_cast<f32x4*>(frow + 4 * i);
            v.x /= norm; v.y /= norm; v.z /= norm; v.w /= norm;
            *reinterpret_cast<f32x4*>(frow + 4 * i) = v;
            bypass_store_f32x4(dst + i, v);
            ssn = fmaf(v.x, v.x, ssn); ssn = fmaf(v.y, v.y, ssn);
            ssn = fmaf(v.z, v.z, ssn); ssn = fmaf(v.w, v.w, ssn);
        }
        ssn += __shfl_xor(ssn, 1); ssn += __shfl_xor(ssn, 2); ssn += __shfl_xor(ssn, 4);
        qn = q[n];
        dloc = fmaf(sqrtf(qn * qn), ssn, LAMBDA_REG);
    }

    // ---- initial block partial (tag 0, buffer 0) ----
    {
        float v = dloc; int idx = n;
        #pragma unroll
        for (int m = 32; m > 0; m >>= 1) {
            float ov = __shfl_xor(v, m);
            int   oi = __shfl_xor(idx, m);
            if (better(ov, oi, v, idx)) { v = ov; idx = oi; }
        }
        if ((tid & 63) == 0) { lds_wave[tid >> 6].v = v; lds_wave[tid >> 6].i = idx; }
        asm volatile("s_waitcnt vmcnt(0)" ::: "memory");  // own FN stores at MALL
        __syncthreads();
        if (tid == 0) {
            Pick p = lds_wave[0];
            #pragma unroll
            for (int w = 1; w < NTHR / 64; ++w) {
                Pick o = lds_wave[w];
                if (better(o.v, o.i, p.v, p.i)) p = o;
            }
            bypass_store_u64(&slots[blk], pack_slot(p.v, p.i, 0));
        }
    }

    for (int t = 0; t < K; ++t) {
        const unsigned want = (unsigned)t;

        // ---- A1: relay duty (blocks 0..7, wave 0): reduce 32 base slots ----
        if (isRelay && tid < 64) {
            const u64* pb = slots + (t & 1) * NBLK + blk * GRP;
            u64 x = 0;
            while (true) {
                if (tid < GRP) x = __hip_atomic_load(pb + tid, __ATOMIC_RELAXED, SCOPE);
                bool ok = (tid >= GRP) || ((unsigned)(x >> 45) == want);
                if (__all(ok)) break;
                __builtin_amdgcn_s_sleep(1);
            }
            asm volatile("" ::: "memory");
            float v = (tid < GRP) ? __uint_as_float((unsigned)x) : -INFINITY;
            int idx = (tid < GRP) ? (int)((x >> 32) & 8191u) : 0x7fffffff;
            #pragma unroll
            for (int m = 32; m > 0; m >>= 1) {
                float ov = __shfl_xor(v, m);
                int   oi = __shfl_xor(idx, m);
                if (better(ov, oi, v, idx)) { v = ov; idx = oi; }
            }
            if (tid == 0)
                bypass_store_u64(&relay[(t & 1) * (NRELAY * 8) + blk * 8],
                                 pack_slot(v, idx, t));
        }

        // ---- A2: leaf poll of 8 relay slots + final argmax (wave 0) ----
        if (tid < 64) {
            const u64* rb = relay + (t & 1) * (NRELAY * 8);
            u64 x = 0;
            while (true) {
                if (tid < NRELAY)
                    x = __hip_atomic_load(rb + tid * 8, __ATOMIC_RELAXED, SCOPE);
                bool ok = (tid >= NRELAY) || ((unsigned)(x >> 45) == want);
                if (__all(ok)) break;
                __builtin_amdgcn_s_sleep(1);
            }
            asm volatile("" ::: "memory");
            float v = (tid < NRELAY) ? __uint_as_float((unsigned)x) : -INFINITY;
            int idx = (tid < NRELAY) ? (int)((x >> 32) & 8191u) : 0x7fffffff;
            #pragma unroll
            for (int m = 32; m > 0; m >>= 1) {
                float ov = __shfl_xor(v, m);
                int   oi = __shfl_xor(idx, m);
                if (better(ov, oi, v, idx)) { v = ov; idx = oi; }
            }
            if (tid == 0) { lds_final.v = v; lds_final.i = idx; }
        }
        __syncthreads();                              // S1
        const float dj = lds_final.v;
        const int   j  = lds_final.i;

        if (blk == 0 && tid == 0) out[t] = j;
        if (t == K - 1) break;

        const float sj = sqrtf(dj);
        const float qj = q[j];

        // ---- B: PLAIN CACHED loads of fn_j + cisT[j][0..t), stage to LDS ----
        f32x4 gv;
        float cv;
        if (tid < 128) gv = FN4[(size_t)j * (D / 4) + tid];
        if (tid < t)   cv = cisT[(size_t)j * K + tid];
        if (tid < 128)
            *reinterpret_cast<f32x4*>(&lds_gj[(tid >> 4) * CS + (tid & 15) * 4]) = gv;
        if (tid < t)   lds_cj[tid] = cv;
        __syncthreads();                              // S2

        // ---- C: dot (LDS x LDS), cd, e, updates ----
        const float* frow = &lds_fn[r * RS + c * CS];
        const float* grow = &lds_gj[c * CS];
        f32x4 a = {0.f, 0.f, 0.f, 0.f};
        #pragma unroll
        for (int i = 0; i < 16; ++i) {
            f32x4 v = *reinterpret_cast<const f32x4*>(frow + 4 * i);
            f32x4 g = *reinterpret_cast<const f32x4*>(grow + 4 * i);
            a.x = fmaf(v.x, g.x, a.x); a.y = fmaf(v.y, g.y, a.y);
            a.z = fmaf(v.z, g.z, a.z); a.w = fmaf(v.w, g.w, a.w);
        }
        float dot = (a.x + a.y) + (a.z + a.w);
        dot += __shfl_xor(dot, 1); dot += __shfl_xor(dot, 2); dot += __shfl_xor(dot, 4);
        float Ljn = sqrtf(qj * qn) * dot;
        if (n == j) Ljn += LAMBDA_REG;

        float cd = 0.f;
        const float* ctrow = &lds_ct[r * CTS];
        for (int tt = c; tt < t; tt += 8)
            cd = fmaf(lds_cj[tt], ctrow[tt], cd);
        cd += __shfl_xor(cd, 1); cd += __shfl_xor(cd, 2); cd += __shfl_xor(cd, 4);

        const float e = (Ljn - cd) / sj;
        if (c == 0) {
            lds_ct[r * CTS + t] = e;
            const float* ep = cisT + (size_t)n * K + t;
            asm volatile("global_store_dword %0, %1, off sc0 sc1"
                         :: "v"(ep), "v"(e) : "memory");
        }
        dloc = fmaf(-e, e, dloc);
        if (n == j) masked = true;

        // ---- block partial for step t+1; publish via plain bypass store ----
        {
            float v = masked ? -INFINITY : dloc; int idx = n;
            #pragma unroll
            for (int m = 32; m > 0; m >>= 1) {
                float ov = __shfl_xor(v, m);
                int   oi = __shfl_xor(idx, m);
                if (better(ov, oi, v, idx)) { v = ov; idx = oi; }
            }
            if ((tid & 63) == 0) { lds_wave[tid >> 6].v = v; lds_wave[tid >> 6].i = idx; }
        }
        asm volatile("s_waitcnt vmcnt(0)" ::: "memory");  // e-store ack'd at MALL
        __syncthreads();                              // S3
        if (tid == 0) {
            Pick p = lds_wave[0];
            #pragma unroll
            for (int w = 1; w < NTHR / 64; ++w) {
                Pick o = lds_wave[w];
                if (better(o.v, o.i, p.v, p.i)) p = o;
            }
            bypass_store_u64(&slots[((t + 1) & 1) * NBLK + blk],
                             pack_slot(p.v, p.i, t + 1));
        }
    }
}

extern "C" void kernel_launch(void* const* d_in, const int* in_sizes, int n_in,
                              void* d_out, int out_size, void* d_ws, size_t ws_size,
                              hipStream_t stream) {
    const float* F = (const float*)d_in[0];
    const float* q = (const float*)d_in[1];
    int* out = (int*)d_out;

    uint8_t* w = (uint8_t*)d_ws;
    u64*   slots = (u64*)(w + 1024);                   // [2][256] u64 = 4 KB
    u64*   relay = (u64*)(w + 8192);                   // [2][8] slots, 64B apart = 1 KB
    float* FN    = (float*)(w + 16384);                // 16 MB
    float* cisT  = (float*)(w + 16384 + (size_t)N * D * 4); // 8 MB

    // invalidate all slot/relay tags each launch (graph replays reuse ws)
    hipMemsetAsync((void*)w, 0xFF, 16384, stream);
    hipLaunchKernelGGL(dpp_kernel, dim3(NBLK), dim3(NTHR), 0, stream,
                       F, q, FN, cisT, slots, relay, out);
}

// Round 8
// 1285.872 us; speedup vs baseline: 5.1574x; 1.0027x over previous
//
#include <hip/hip_runtime.h>
#include <math.h>
#include <stdint.h>

// Greedy DPP MAP — persistent kernel, round 8.
// N=8192, D=512, K=256. 256 blocks x 256 threads (1 block/CU); 8 lanes/row.
// vs round 7: star-topology argmax exchange with per-line poll pressure = 1.
//  - base slots spread to one 64B line per block (256 lines); ONLY root
//    (block 0) polls them (4 lines/lane on wave0 -> 1 poller per line).
//  - root butterfly-reduces 256 partials, fans winner out to 256 private
//    64B mailbox lines (4 bypass stores/lane, fire-and-forget).
//  - each leaf polls ITS OWN mailbox line with a single lane.
// r6/r7 had ~256 pollers per line (8192/32 and 2048/8) -> MALL queue drain
// dominated the step; this makes every polled line single-poller.
// fn_j / cisT[j] prefix remain PLAIN CACHED loads (r7 win, FETCH 19->12MB);
// e-stores / FN-init / slot+mailbox publishes remain sc0+sc1 bypass.
// No fences / ordered atomics anywhere.

#define N 8192
#define D 512
#define K 256
#define LAMBDA_REG 0.01f
#define NBLK 256
#define NTHR 256
#define ROWS 32          // rows per block
#define RS   560         // floats per row in lds_fn
#define CS   68          // floats per 64-float chunk (64 + 4 pad)
#define CTS  264         // floats per row in lds_ct
#define SSTR 8           // u64s per slot/mailbox line (64B)
#define SCOPE __HIP_MEMORY_SCOPE_AGENT

typedef unsigned long long u64;
typedef float f32x4 __attribute__((ext_vector_type(4)));

struct __align__(8) Pick { float v; int i; };

__device__ __forceinline__ bool better(float av, int ai, float bv, int bi) {
    // first-max semantics (jnp.argmax tie-break: lowest index wins)
    return (av > bv) || (av == bv && ai < bi);
}

__device__ __forceinline__ u64 pack_slot(float v, int idx, int tag) {
    unsigned hi = ((unsigned)tag << 13) | (unsigned)idx;   // idx < 8192
    return ((u64)hi << 32) | (u64)__float_as_uint(v);
}

__device__ __forceinline__ void bypass_store_u64(u64* p, u64 v) {
    asm volatile("global_store_dwordx2 %0, %1, off sc0 sc1"
                 :: "v"(p), "v"(v) : "memory");
}

__device__ __forceinline__ void bypass_store_f32x4(const f32x4* p, f32x4 v) {
    asm volatile("global_store_dwordx4 %0, %1, off sc0 sc1"
                 :: "v"(p), "v"(v) : "memory");
}

__global__ __launch_bounds__(NTHR, 1) void dpp_kernel(
        const float* __restrict__ F, const float* __restrict__ q,
        float* __restrict__ FN, float* __restrict__ cisT,
        u64* __restrict__ slots, u64* __restrict__ mbox,
        int* __restrict__ out)
{
    const int tid = threadIdx.x;
    const int blk = blockIdx.x;
    const int r   = tid >> 3;        // local row 0..31
    const int c   = tid & 7;         // chunk lane 0..7
    const int n   = blk * ROWS + r;  // global row

    __shared__ __align__(16) float lds_fn[ROWS * RS];   // own FN rows
    __shared__ __align__(16) float lds_ct[ROWS * CTS];  // own cis prefix
    __shared__ __align__(16) float lds_gj[8 * CS];      // fn_j staged
    __shared__ __align__(16) float lds_cj[K];           // cisT[j][0..t)
    __shared__ Pick lds_wave[NTHR / 64];
    __shared__ Pick lds_final;

    const f32x4* F4  = reinterpret_cast<const f32x4*>(F);
    f32x4*       FN4 = reinterpret_cast<f32x4*>(FN);

    // ---- init: load own row, normalize; FN written via MALL-bypass stores ----
    float dloc, qn;
    bool  masked = false;
    {
        const f32x4* src = F4 + (size_t)n * (D / 4) + c * 16;
        float* frow = &lds_fn[r * RS + c * CS];
        float ss = 0.f;
        #pragma unroll
        for (int i = 0; i < 16; ++i) {
            f32x4 v = src[i];
            *reinterpret_cast<f32x4*>(frow + 4 * i) = v;
            ss = fmaf(v.x, v.x, ss); ss = fmaf(v.y, v.y, ss);
            ss = fmaf(v.z, v.z, ss); ss = fmaf(v.w, v.w, ss);
        }
        ss += __shfl_xor(ss, 1); ss += __shfl_xor(ss, 2); ss += __shfl_xor(ss, 4);
        const float norm = sqrtf(ss);
        f32x4* dst = FN4 + (size_t)n * (D / 4) + c * 16;
        float ssn = 0.f;
        #pragma unroll
        for (int i = 0; i < 16; ++i) {
            f32x4 v = *reinterpret_cast<f32x4*>(frow + 4 * i);
            v.x /= norm; v.y /= norm; v.z /= norm; v.w /= norm;
            *reinterpret_cast<f32x4*>(frow + 4 * i) = v;
            bypass_store_f32x4(dst + i, v);
            ssn = fmaf(v.x, v.x, ssn); ssn = fmaf(v.y, v.y, ssn);
            ssn = fmaf(v.z, v.z, ssn); ssn = fmaf(v.w, v.w, ssn);
        }
        ssn += __shfl_xor(ssn, 1); ssn += __shfl_xor(ssn, 2); ssn += __shfl_xor(ssn, 4);
        qn = q[n];
        dloc = fmaf(sqrtf(qn * qn), ssn, LAMBDA_REG);
    }

    // ---- initial block partial (tag 0, buffer 0) ----
    {
        float v = dloc; int idx = n;
        #pragma unroll
        for (int m = 32; m > 0; m >>= 1) {
            float ov = __shfl_xor(v, m);
            int   oi = __shfl_xor(idx, m);
            if (better(ov, oi, v, idx)) { v = ov; idx = oi; }
        }
        if ((tid & 63) == 0) { lds_wave[tid >> 6].v = v; lds_wave[tid >> 6].i = idx; }
        asm volatile("s_waitcnt vmcnt(0)" ::: "memory");  // own FN stores at MALL
        __syncthreads();
        if (tid == 0) {
            Pick p = lds_wave[0];
            #pragma unroll
            for (int w = 1; w < NTHR / 64; ++w) {
                Pick o = lds_wave[w];
                if (better(o.v, o.i, p.v, p.i)) p = o;
            }
            bypass_store_u64(&slots[blk * SSTR], pack_slot(p.v, p.i, 0));
        }
    }

    for (int t = 0; t < K; ++t) {
        const unsigned want = (unsigned)t;

        // ---- A: winner determination ----
        if (blk == 0) {
            // root: wave0 polls all 256 slot lines (4 distinct lines/lane)
            if (tid < 64) {
                const u64* pb = slots + (t & 1) * NBLK * SSTR;
                u64 x0, x1, x2, x3;
                while (true) {
                    x0 = __hip_atomic_load(pb + (tid * 4 + 0) * SSTR, __ATOMIC_RELAXED, SCOPE);
                    x1 = __hip_atomic_load(pb + (tid * 4 + 1) * SSTR, __ATOMIC_RELAXED, SCOPE);
                    x2 = __hip_atomic_load(pb + (tid * 4 + 2) * SSTR, __ATOMIC_RELAXED, SCOPE);
                    x3 = __hip_atomic_load(pb + (tid * 4 + 3) * SSTR, __ATOMIC_RELAXED, SCOPE);
                    bool ok = ((unsigned)(x0 >> 45) == want) &&
                              ((unsigned)(x1 >> 45) == want) &&
                              ((unsigned)(x2 >> 45) == want) &&
                              ((unsigned)(x3 >> 45) == want);
                    if (__all(ok)) break;
                    __builtin_amdgcn_s_sleep(1);
                }
                asm volatile("" ::: "memory");
                float v = __uint_as_float((unsigned)x0);
                int idx = (int)((x0 >> 32) & 8191u);
                {
                    float w = __uint_as_float((unsigned)x1); int k1 = (int)((x1 >> 32) & 8191u);
                    if (better(w, k1, v, idx)) { v = w; idx = k1; }
                    w = __uint_as_float((unsigned)x2); k1 = (int)((x2 >> 32) & 8191u);
                    if (better(w, k1, v, idx)) { v = w; idx = k1; }
                    w = __uint_as_float((unsigned)x3); k1 = (int)((x3 >> 32) & 8191u);
                    if (better(w, k1, v, idx)) { v = w; idx = k1; }
                }
                #pragma unroll
                for (int m = 32; m > 0; m >>= 1) {   // butterfly: all lanes converge
                    float ov = __shfl_xor(v, m);
                    int   oi = __shfl_xor(idx, m);
                    if (better(ov, oi, v, idx)) { v = ov; idx = oi; }
                }
                // fan out winner to 256 private mailbox lines
                const u64 msg = pack_slot(v, idx, t);
                u64* mb = mbox + (t & 1) * NBLK * SSTR;
                bypass_store_u64(mb + (tid * 4 + 0) * SSTR, msg);
                bypass_store_u64(mb + (tid * 4 + 1) * SSTR, msg);
                bypass_store_u64(mb + (tid * 4 + 2) * SSTR, msg);
                bypass_store_u64(mb + (tid * 4 + 3) * SSTR, msg);
                if (tid == 0) { lds_final.v = v; lds_final.i = idx; }
            }
        } else {
            // leaf: single lane polls its own mailbox line
            if (tid == 0) {
                const u64* mp = mbox + ((t & 1) * NBLK + blk) * SSTR;
                u64 x;
                while (true) {
                    x = __hip_atomic_load(mp, __ATOMIC_RELAXED, SCOPE);
                    if ((unsigned)(x >> 45) == want) break;
                    __builtin_amdgcn_s_sleep(1);
                }
                asm volatile("" ::: "memory");
                lds_final.v = __uint_as_float((unsigned)x);
                lds_final.i = (int)((x >> 32) & 8191u);
            }
        }
        __syncthreads();                              // S1
        const float dj = lds_final.v;
        const int   j  = lds_final.i;

        if (blk == 0 && tid == 0) out[t] = j;
        if (t == K - 1) break;

        const float sj = sqrtf(dj);
        const float qj = q[j];

        // ---- B: PLAIN CACHED loads of fn_j + cisT[j][0..t), stage to LDS ----
        f32x4 gv;
        float cv;
        if (tid < 128) gv = FN4[(size_t)j * (D / 4) + tid];
        if (tid < t)   cv = cisT[(size_t)j * K + tid];
        if (tid < 128)
            *reinterpret_cast<f32x4*>(&lds_gj[(tid >> 4) * CS + (tid & 15) * 4]) = gv;
        if (tid < t)   lds_cj[tid] = cv;
        __syncthreads();                              // S2

        // ---- C: dot (LDS x LDS), cd, e, updates ----
        const float* frow = &lds_fn[r * RS + c * CS];
        const float* grow = &lds_gj[c * CS];
        f32x4 a = {0.f, 0.f, 0.f, 0.f};
        #pragma unroll
        for (int i = 0; i < 16; ++i) {
            f32x4 v = *reinterpret_cast<const f32x4*>(frow + 4 * i);
            f32x4 g = *reinterpret_cast<const f32x4*>(grow + 4 * i);
            a.x = fmaf(v.x, g.x, a.x); a.y = fmaf(v.y, g.y, a.y);
            a.z = fmaf(v.z, g.z, a.z); a.w = fmaf(v.w, g.w, a.w);
        }
        float dot = (a.x + a.y) + (a.z + a.w);
        dot += __shfl_xor(dot, 1); dot += __shfl_xor(dot, 2); dot += __shfl_xor(dot, 4);
        float Ljn = sqrtf(qj * qn) * dot;
        if (n == j) Ljn += LAMBDA_REG;

        float cd = 0.f;
        const float* ctrow = &lds_ct[r * CTS];
        for (int tt = c; tt < t; tt += 8)
            cd = fmaf(lds_cj[tt], ctrow[tt], cd);
        cd += __shfl_xor(cd, 1); cd += __shfl_xor(cd, 2); cd += __shfl_xor(cd, 4);

        const float e = (Ljn - cd) / sj;
        if (c == 0) {
            lds_ct[r * CTS + t] = e;
            const float* ep = cisT + (size_t)n * K + t;
            asm volatile("global_store_dword %0, %1, off sc0 sc1"
                         :: "v"(ep), "v"(e) : "memory");
        }
        dloc = fmaf(-e, e, dloc);
        if (n == j) masked = true;

        // ---- block partial for step t+1; publish via plain bypass store ----
        {
            float v = masked ? -INFINITY : dloc; int idx = n;
            #pragma unroll
            for (int m = 32; m > 0; m >>= 1) {
                float ov = __shfl_xor(v, m);
                int   oi = __shfl_xor(idx, m);
                if (better(ov, oi, v, idx)) { v = ov; idx = oi; }
            }
            if ((tid & 63) == 0) { lds_wave[tid >> 6].v = v; lds_wave[tid >> 6].i = idx; }
        }
        asm volatile("s_waitcnt vmcnt(0)" ::: "memory");  // e-store ack'd at MALL
        __syncthreads();                              // S3
        if (tid == 0) {
            Pick p = lds_wave[0];
            #pragma unroll
            for (int w = 1; w < NTHR / 64; ++w) {
                Pick o = lds_wave[w];
                if (better(o.v, o.i, p.v, p.i)) p = o;
            }
            bypass_store_u64(&slots[(((t + 1) & 1) * NBLK + blk) * SSTR],
                             pack_slot(p.v, p.i, t + 1));
        }
    }
}

extern "C" void kernel_launch(void* const* d_in, const int* in_sizes, int n_in,
                              void* d_out, int out_size, void* d_ws, size_t ws_size,
                              hipStream_t stream) {
    const float* F = (const float*)d_in[0];
    const float* q = (const float*)d_in[1];
    int* out = (int*)d_out;

    uint8_t* w = (uint8_t*)d_ws;
    u64*   slots = (u64*)(w + 4096);            // [2][256] 64B lines = 32 KB
    u64*   mbox  = (u64*)(w + 4096 + 32768);    // [2][256] 64B lines = 32 KB
    float* FN    = (float*)(w + 131072);                      // 16 MB
    float* cisT  = (float*)(w + 131072 + (size_t)N * D * 4);  // 8 MB

    // invalidate all slot/mailbox tags each launch (graph replays reuse ws)
    hipMemsetAsync((void*)w, 0xFF, 131072, stream);
    hipLaunchKernelGGL(dpp_kernel, dim3(NBLK), dim3(NTHR), 0, stream,
                       F, q, FN, cisT, slots, mbox, out);
}

// Round 9
// 1176.914 us; speedup vs baseline: 5.6349x; 1.0926x over previous
//
#include <hip/hip_runtime.h>
#include <math.h>
#include <stdint.h>

// Greedy DPP MAP — persistent kernel, round 9.
// N=8192, D=512, K=256. 256 blocks x 256 threads (1 block/CU); 8 lanes/row.
// vs round 8: ONE-hop exchange. Every block's wave0 polls ALL 256 spread
// slot lines (4 lines/lane, r8's root pattern replicated everywhere) and
// butterfly-reduces to the winner directly — no root, no fan-out hop.
// Slots stay one-64B-line-per-block (single writer per line, no sharing).
// B-phase staging split: waves 0-1 fetch fn_j while waves 2-3 fetch cisT[j]
// prefix (parallel MALL streams). fn_j / cj remain PLAIN CACHED loads
// (dispatch-acquire + write-once-before-read + read-once-ever make it safe).
// e-stores / FN-init / slot publishes remain sc0+sc1 bypass.
// No fences / ordered atomics anywhere.

#define N 8192
#define D 512
#define K 256
#define LAMBDA_REG 0.01f
#define NBLK 256
#define NTHR 256
#define ROWS 32          // rows per block
#define RS   560         // floats per row in lds_fn
#define CS   68          // floats per 64-float chunk (64 + 4 pad)
#define CTS  264         // floats per row in lds_ct
#define SSTR 8           // u64s per slot line (64B)
#define SCOPE __HIP_MEMORY_SCOPE_AGENT

typedef unsigned long long u64;
typedef float f32x4 __attribute__((ext_vector_type(4)));

struct __align__(8) Pick { float v; int i; };

__device__ __forceinline__ bool better(float av, int ai, float bv, int bi) {
    // first-max semantics (jnp.argmax tie-break: lowest index wins)
    return (av > bv) || (av == bv && ai < bi);
}

__device__ __forceinline__ u64 pack_slot(float v, int idx, int tag) {
    unsigned hi = ((unsigned)tag << 13) | (unsigned)idx;   // idx < 8192
    return ((u64)hi << 32) | (u64)__float_as_uint(v);
}

__device__ __forceinline__ void bypass_store_u64(u64* p, u64 v) {
    asm volatile("global_store_dwordx2 %0, %1, off sc0 sc1"
                 :: "v"(p), "v"(v) : "memory");
}

__device__ __forceinline__ void bypass_store_f32x4(const f32x4* p, f32x4 v) {
    asm volatile("global_store_dwordx4 %0, %1, off sc0 sc1"
                 :: "v"(p), "v"(v) : "memory");
}

__global__ __launch_bounds__(NTHR, 1) void dpp_kernel(
        const float* __restrict__ F, const float* __restrict__ q,
        float* __restrict__ FN, float* __restrict__ cisT,
        u64* __restrict__ slots, int* __restrict__ out)
{
    const int tid = threadIdx.x;
    const int blk = blockIdx.x;
    const int r   = tid >> 3;        // local row 0..31
    const int c   = tid & 7;         // chunk lane 0..7
    const int n   = blk * ROWS + r;  // global row

    __shared__ __align__(16) float lds_fn[ROWS * RS];   // own FN rows
    __shared__ __align__(16) float lds_ct[ROWS * CTS];  // own cis prefix
    __shared__ __align__(16) float lds_gj[8 * CS];      // fn_j staged
    __shared__ __align__(16) float lds_cj[K];           // cisT[j][0..t)
    __shared__ Pick lds_wave[NTHR / 64];
    __shared__ Pick lds_final;

    const f32x4* F4  = reinterpret_cast<const f32x4*>(F);
    f32x4*       FN4 = reinterpret_cast<f32x4*>(FN);

    // ---- init: load own row, normalize; FN written via MALL-bypass stores ----
    float dloc, qn;
    bool  masked = false;
    {
        const f32x4* src = F4 + (size_t)n * (D / 4) + c * 16;
        float* frow = &lds_fn[r * RS + c * CS];
        float ss = 0.f;
        #pragma unroll
        for (int i = 0; i < 16; ++i) {
            f32x4 v = src[i];
            *reinterpret_cast<f32x4*>(frow + 4 * i) = v;
            ss = fmaf(v.x, v.x, ss); ss = fmaf(v.y, v.y, ss);
            ss = fmaf(v.z, v.z, ss); ss = fmaf(v.w, v.w, ss);
        }
        ss += __shfl_xor(ss, 1); ss += __shfl_xor(ss, 2); ss += __shfl_xor(ss, 4);
        const float norm = sqrtf(ss);
        f32x4* dst = FN4 + (size_t)n * (D / 4) + c * 16;
        float ssn = 0.f;
        #pragma unroll
        for (int i = 0; i < 16; ++i) {
            f32x4 v = *reinterpret_cast<f32x4*>(frow + 4 * i);
            v.x /= norm; v.y /= norm; v.z /= norm; v.w /= norm;
            *reinterpret_cast<f32x4*>(frow + 4 * i) = v;
            bypass_store_f32x4(dst + i, v);
            ssn = fmaf(v.x, v.x, ssn); ssn = fmaf(v.y, v.y, ssn);
            ssn = fmaf(v.z, v.z, ssn); ssn = fmaf(v.w, v.w, ssn);
        }
        ssn += __shfl_xor(ssn, 1); ssn += __shfl_xor(ssn, 2); ssn += __shfl_xor(ssn, 4);
        qn = q[n];
        dloc = fmaf(sqrtf(qn * qn), ssn, LAMBDA_REG);
    }

    // ---- initial block partial (tag 0, buffer 0) ----
    {
        float v = dloc; int idx = n;
        #pragma unroll
        for (int m = 32; m > 0; m >>= 1) {
            float ov = __shfl_xor(v, m);
            int   oi = __shfl_xor(idx, m);
            if (better(ov, oi, v, idx)) { v = ov; idx = oi; }
        }
        if ((tid & 63) == 0) { lds_wave[tid >> 6].v = v; lds_wave[tid >> 6].i = idx; }
        asm volatile("s_waitcnt vmcnt(0)" ::: "memory");  // own FN stores at MALL
        __syncthreads();
        if (tid == 0) {
            Pick p = lds_wave[0];
            #pragma unroll
            for (int w = 1; w < NTHR / 64; ++w) {
                Pick o = lds_wave[w];
                if (better(o.v, o.i, p.v, p.i)) p = o;
            }
            bypass_store_u64(&slots[blk * SSTR], pack_slot(p.v, p.i, 0));
        }
    }

    for (int t = 0; t < K; ++t) {
        const unsigned want = (unsigned)t;

        // ---- A: 1-hop — wave0 of EVERY block polls all 256 spread lines ----
        if (tid < 64) {
            const u64* pb = slots + (t & 1) * NBLK * SSTR;
            u64 x0, x1, x2, x3;
            while (true) {
                x0 = __hip_atomic_load(pb + (tid * 4 + 0) * SSTR, __ATOMIC_RELAXED, SCOPE);
                x1 = __hip_atomic_load(pb + (tid * 4 + 1) * SSTR, __ATOMIC_RELAXED, SCOPE);
                x2 = __hip_atomic_load(pb + (tid * 4 + 2) * SSTR, __ATOMIC_RELAXED, SCOPE);
                x3 = __hip_atomic_load(pb + (tid * 4 + 3) * SSTR, __ATOMIC_RELAXED, SCOPE);
                bool ok = ((unsigned)(x0 >> 45) == want) &&
                          ((unsigned)(x1 >> 45) == want) &&
                          ((unsigned)(x2 >> 45) == want) &&
                          ((unsigned)(x3 >> 45) == want);
                if (__all(ok)) break;
                __builtin_amdgcn_s_sleep(1);
            }
            asm volatile("" ::: "memory");
            float v = __uint_as_float((unsigned)x0);
            int idx = (int)((x0 >> 32) & 8191u);
            {
                float w = __uint_as_float((unsigned)x1); int k1 = (int)((x1 >> 32) & 8191u);
                if (better(w, k1, v, idx)) { v = w; idx = k1; }
                w = __uint_as_float((unsigned)x2); k1 = (int)((x2 >> 32) & 8191u);
                if (better(w, k1, v, idx)) { v = w; idx = k1; }
                w = __uint_as_float((unsigned)x3); k1 = (int)((x3 >> 32) & 8191u);
                if (better(w, k1, v, idx)) { v = w; idx = k1; }
            }
            #pragma unroll
            for (int m = 32; m > 0; m >>= 1) {
                float ov = __shfl_xor(v, m);
                int   oi = __shfl_xor(idx, m);
                if (better(ov, oi, v, idx)) { v = ov; idx = oi; }
            }
            if (tid == 0) { lds_final.v = v; lds_final.i = idx; }
        }
        __syncthreads();                              // S1
        const float dj = lds_final.v;
        const int   j  = lds_final.i;

        if (blk == 0 && tid == 0) out[t] = j;
        if (t == K - 1) break;

        const float sj = sqrtf(dj);
        const float qj = q[j];

        // ---- B: parallel staging — waves 0-1: fn_j; waves 2-3: cisT[j] ----
        f32x4 gv;
        float cv0, cv1;
        int   tt0 = tid - 128, tt1 = tid;   // tt1 = tid-128+128
        if (tid < 128) {
            gv = FN4[(size_t)j * (D / 4) + tid];
        } else {
            if (tt0 < t) cv0 = cisT[(size_t)j * K + tt0];
            if (tt1 < t) cv1 = cisT[(size_t)j * K + tt1];
        }
        if (tid < 128) {
            *reinterpret_cast<f32x4*>(&lds_gj[(tid >> 4) * CS + (tid & 15) * 4]) = gv;
        } else {
            if (tt0 < t) lds_cj[tt0] = cv0;
            if (tt1 < t) lds_cj[tt1] = cv1;
        }
        __syncthreads();                              // S2

        // ---- C: dot (LDS x LDS), cd, e, updates ----
        const float* frow = &lds_fn[r * RS + c * CS];
        const float* grow = &lds_gj[c * CS];
        f32x4 a = {0.f, 0.f, 0.f, 0.f};
        #pragma unroll
        for (int i = 0; i < 16; ++i) {
            f32x4 v = *reinterpret_cast<const f32x4*>(frow + 4 * i);
            f32x4 g = *reinterpret_cast<const f32x4*>(grow + 4 * i);
            a.x = fmaf(v.x, g.x, a.x); a.y = fmaf(v.y, g.y, a.y);
            a.z = fmaf(v.z, g.z, a.z); a.w = fmaf(v.w, g.w, a.w);
        }
        float dot = (a.x + a.y) + (a.z + a.w);
        dot += __shfl_xor(dot, 1); dot += __shfl_xor(dot, 2); dot += __shfl_xor(dot, 4);
        float Ljn = sqrtf(qj * qn) * dot;
        if (n == j) Ljn += LAMBDA_REG;

        float cd = 0.f;
        const float* ctrow = &lds_ct[r * CTS];
        for (int tt = c; tt < t; tt += 8)
            cd = fmaf(lds_cj[tt], ctrow[tt], cd);
        cd += __shfl_xor(cd, 1); cd += __shfl_xor(cd, 2); cd += __shfl_xor(cd, 4);

        const float e = (Ljn - cd) / sj;
        if (c == 0) {
            lds_ct[r * CTS + t] = e;
            const float* ep = cisT + (size_t)n * K + t;
            asm volatile("global_store_dword %0, %1, off sc0 sc1"
                         :: "v"(ep), "v"(e) : "memory");
        }
        dloc = fmaf(-e, e, dloc);
        if (n == j) masked = true;

        // ---- block partial for step t+1; publish via plain bypass store ----
        {
            float v = masked ? -INFINITY : dloc; int idx = n;
            #pragma unroll
            for (int m = 32; m > 0; m >>= 1) {
                float ov = __shfl_xor(v, m);
                int   oi = __shfl_xor(idx, m);
                if (better(ov, oi, v, idx)) { v = ov; idx = oi; }
            }
            if ((tid & 63) == 0) { lds_wave[tid >> 6].v = v; lds_wave[tid >> 6].i = idx; }
        }
        asm volatile("s_waitcnt vmcnt(0)" ::: "memory");  // e-store ack'd at MALL
        __syncthreads();                              // S3
        if (tid == 0) {
            Pick p = lds_wave[0];
            #pragma unroll
            for (int w = 1; w < NTHR / 64; ++w) {
                Pick o = lds_wave[w];
                if (better(o.v, o.i, p.v, p.i)) p = o;
            }
            bypass_store_u64(&slots[(((t + 1) & 1) * NBLK + blk) * SSTR],
                             pack_slot(p.v, p.i, t + 1));
        }
    }
}

extern "C" void kernel_launch(void* const* d_in, const int* in_sizes, int n_in,
                              void* d_out, int out_size, void* d_ws, size_t ws_size,
                              hipStream_t stream) {
    const float* F = (const float*)d_in[0];
    const float* q = (const float*)d_in[1];
    int* out = (int*)d_out;

    uint8_t* w = (uint8_t*)d_ws;
    u64*   slots = (u64*)(w + 4096);            // [2][256] 64B lines = 32 KB
    float* FN    = (float*)(w + 131072);                      // 16 MB
    float* cisT  = (float*)(w + 131072 + (size_t)N * D * 4);  // 8 MB

    // invalidate all slot tags each launch (graph replays reuse ws)
    hipMemsetAsync((void*)w, 0xFF, 65536, stream);
    hipLaunchKernelGGL(dpp_kernel, dim3(NBLK), dim3(NTHR), 0, stream,
                       F, q, FN, cisT, slots, out);
}